// Round 4
// baseline (743.328 us; speedup 1.0000x reference)
//
#include <hip/hip_runtime.h>
#include <math.h>

// Problem constants: B=4, Nq=2048, Nf=16384, D=3, C=768
#define Bt  4
#define NQ  2048
#define NF  16384
#define CC  768

// ---- old-path (fallback) tile params ----
#define QT  128     // q-rows per old main block
#define CT  96      // channels per old main block
#define BK  128     // Nf chunk per LDS stage (old)
#define THR 512     // threads per old main block
#define NCH (NF / BK)

// ---- new-path params ----
#define NFS   4                  // Nf splits (partial sums)
#define KC    (NF / NFS)         // 4096 k per block
#define BK2   16                 // k per LDS chunk
#define NCH2  (KC / BK2)         // 256 chunks per block
#define TILEB (CC * BK2 * 2)     // 24576 B per bf16 v-tile (one chunk, all 768 c)
#define NTILE (Bt * (NF / BK2))  // 4096 tiles total (96 MB, same as before)

#define SCALE_LOG2E 0.8329080161227079f   // (1/sqrt(3)) * log2(e)

typedef __attribute__((ext_vector_type(8)))  short  short8;
typedef __attribute__((ext_vector_type(4)))  float  floatx4;
typedef __attribute__((ext_vector_type(16))) float  floatx16;

#if __has_builtin(__builtin_amdgcn_exp2f)
#define EXP2F(x) __builtin_amdgcn_exp2f(x)
#else
#define EXP2F(x) __expf((x) * 0.6931471805599453f)
#endif

static __device__ __forceinline__ float relu(float x) { return fmaxf(x, 0.0f); }

// fp32 -> bf16 bits, round-to-nearest-even (inputs finite, non-NaN)
static __device__ __forceinline__ unsigned int f2bf(float f) {
    unsigned int u = __float_as_uint(f);
    u += 0x7fffu + ((u >> 16) & 1u);
    return u >> 16;
}

// direct-to-LDS 16B DMA (linear dest: wave-uniform base + lane*16)
#define GLDS16(gsrc, ldst)                                                        \
    __builtin_amdgcn_global_load_lds(                                             \
        (const __attribute__((address_space(1))) unsigned int*)(gsrc),            \
        (__attribute__((address_space(3))) unsigned int*)(ldst), 16, 0, 0)

// ---------------------------------------------------------------------------
// Kernel 1 (prep): qp = relu(q@W1^T+b1)*SCALE*log2e (float4, w=0 placeholder)
//                  kp = relu(k@W2^T+b2) stored TIGHT float3
// ---------------------------------------------------------------------------
__global__ __launch_bounds__(256) void prep_kernel(
    const float* __restrict__ q, const float* __restrict__ k,
    const float* __restrict__ W1, const float* __restrict__ b1,
    const float* __restrict__ W2, const float* __restrict__ b2,
    float4* __restrict__ qp, float* __restrict__ kp3)
{
    int idx = blockIdx.x * 256 + threadIdx.x;
    if (idx < Bt * NQ) {
        const float* r = q + (size_t)idx * 3;
        float x0 = r[0], x1 = r[1], x2 = r[2];
        float4 o;
        o.x = relu(fmaf(W1[0], x0, fmaf(W1[1], x1, fmaf(W1[2], x2, b1[0])))) * SCALE_LOG2E;
        o.y = relu(fmaf(W1[3], x0, fmaf(W1[4], x1, fmaf(W1[5], x2, b1[1])))) * SCALE_LOG2E;
        o.z = relu(fmaf(W1[6], x0, fmaf(W1[7], x1, fmaf(W1[8], x2, b1[2])))) * SCALE_LOG2E;
        o.w = 0.0f;
        qp[idx] = o;
    } else {
        int kidx = idx - Bt * NQ;   // < Bt*NF by grid construction
        const float* r = k + (size_t)kidx * 3;
        float x0 = r[0], x1 = r[1], x2 = r[2];
        float* dst = kp3 + (size_t)kidx * 3;
        dst[0] = relu(fmaf(W2[0], x0, fmaf(W2[1], x1, fmaf(W2[2], x2, b2[0]))));
        dst[1] = relu(fmaf(W2[3], x0, fmaf(W2[4], x1, fmaf(W2[5], x2, b2[1]))));
        dst[2] = relu(fmaf(W2[6], x0, fmaf(W2[7], x1, fmaf(W2[8], x2, b2[2]))));
    }
}

// ---------------------------------------------------------------------------
// Kernel 2 (stats): rowmax' (log2 domain) and 1/sum(exp2). Writes qp.w = -rm.
// ---------------------------------------------------------------------------
__global__ __launch_bounds__(256) void stats_kernel(
    float4* __restrict__ qp, const float* __restrict__ kp3,
    float2* __restrict__ rstat)
{
    __shared__ float wredA[4][16];
    __shared__ float wredB[4][16];

    const int bid  = blockIdx.x;
    const int b    = bid >> 7;            // NQ/16 = 128 blocks per batch
    const int q0   = (bid & 127) * 16;
    const int t    = threadIdx.x;
    const int wv   = t >> 6;
    const int lane = t & 63;

    float qx[16], qy[16], qz[16];
#pragma unroll
    for (int i = 0; i < 16; ++i) {
        float4 qv = qp[b * NQ + q0 + i];
        qx[i] = qv.x; qy[i] = qv.y; qz[i] = qv.z;
    }
    const float* kpb = kp3 + (size_t)b * NF * 3;

    float pmax[16];
#pragma unroll
    for (int i = 0; i < 16; ++i) pmax[i] = -1e30f;
    for (int m = t; m < NF; m += 256) {
        float kx = kpb[3 * m], ky = kpb[3 * m + 1], kz = kpb[3 * m + 2];
#pragma unroll
        for (int i = 0; i < 16; ++i) {
            float s = fmaf(qx[i], kx, fmaf(qy[i], ky, qz[i] * kz));
            pmax[i] = fmaxf(pmax[i], s);
        }
    }
#pragma unroll
    for (int off = 32; off >= 1; off >>= 1)
#pragma unroll
        for (int i = 0; i < 16; ++i)
            pmax[i] = fmaxf(pmax[i], __shfl_xor(pmax[i], off, 64));
    if (lane == 0)
#pragma unroll
        for (int i = 0; i < 16; ++i) wredA[wv][i] = pmax[i];
    __syncthreads();

    float rowmax[16];
#pragma unroll
    for (int i = 0; i < 16; ++i)
        rowmax[i] = fmaxf(fmaxf(wredA[0][i], wredA[1][i]),
                          fmaxf(wredA[2][i], wredA[3][i]));

    float psum[16];
#pragma unroll
    for (int i = 0; i < 16; ++i) psum[i] = 0.0f;
    for (int m = t; m < NF; m += 256) {
        float kx = kpb[3 * m], ky = kpb[3 * m + 1], kz = kpb[3 * m + 2];
#pragma unroll
        for (int i = 0; i < 16; ++i) {
            float s = fmaf(qx[i], kx, fmaf(qy[i], ky, qz[i] * kz));
            psum[i] += EXP2F(s - rowmax[i]);
        }
    }
#pragma unroll
    for (int off = 32; off >= 1; off >>= 1)
#pragma unroll
        for (int i = 0; i < 16; ++i)
            psum[i] += __shfl_xor(psum[i], off, 64);
    if (lane == 0)
#pragma unroll
        for (int i = 0; i < 16; ++i) wredB[wv][i] = psum[i];
    __syncthreads();

    if (t < 16) {
        float m = fmaxf(fmaxf(wredA[0][t], wredA[1][t]),
                        fmaxf(wredA[2][t], wredA[3][t]));
        float l = wredB[0][t] + wredB[1][t] + wredB[2][t] + wredB[3][t];
        int row = b * NQ + q0 + t;
        rstat[row] = make_float2(m, 1.0f / l);
        qp[row].w = -m;
    }
}

// ---------------------------------------------------------------------------
// Kernel 2b (prep_v): v f32 -> bf16, pre-arranged in the exact swizzled
// B-fragment tile layout for BK2=16 chunks.
// Tile (b, ch): byte(c, k) = c*32 + slot*16 + (k&7)*2,
//   slot = (k>>3) ^ ((c>>2)&1)
// Read side (main): lane col c, slot = (l>>5) ^ ((l>>2)&1) -> granule index
// (c*2 + slot) covers all 8 residues mod 8 per 8 consecutive lanes
// => conflict-free ds_read_b128.
// ---------------------------------------------------------------------------
__global__ __launch_bounds__(256) void prep_v_kernel(
    const float* __restrict__ v, char* __restrict__ vpk)
{
    __shared__ float lt[16][132];         // 16 k-rows x 128 c (+4 pad)
    const int t   = threadIdx.x;
    const int bid = blockIdx.x;           // Bt * 1024 * 6 blocks
    const int cb  = bid % 6;
    const int ch  = (bid / 6) & 1023;
    const int b   = bid / (6 * 1024);
    const int c0  = cb * 128;

    // load 16 k x 128 c f32 tile, coalesced
    const float* vb = v + ((size_t)b * NF + (size_t)ch * BK2) * CC + c0;
    const int c4 = (t & 31) * 4;
#pragma unroll
    for (int r2 = 0; r2 < 2; ++r2) {
        const int row = (t >> 5) + 8 * r2;
        *(float4*)&lt[row][c4] = *(const float4*)(vb + (size_t)row * CC + c4);
    }
    __syncthreads();

    // each thread emits one 16B slot: c = t>>1 (local), slot = t&1 (8 k's)
    const int c  = t >> 1;
    const int sl = t & 1;
    unsigned int dw[4];
#pragma unroll
    for (int i = 0; i < 4; ++i) {
        float a  = lt[8 * sl + 2 * i][c];
        float b2 = lt[8 * sl + 2 * i + 1][c];
        asm("v_cvt_pk_bf16_f32 %0, %1, %2" : "=v"(dw[i]) : "v"(a), "v"(b2));
    }
    const int cgl = c0 + c;
    char* dst = vpk + (size_t)(b * (NF / BK2) + ch) * TILEB
              + ((size_t)cgl << 5)
              + ((sl ^ ((cgl >> 2) & 1)) << 4);
    uint4 u; u.x = dw[0]; u.y = dw[1]; u.z = dw[2]; u.w = dw[3];
    *(uint4*)dst = u;
}

// ---------------------------------------------------------------------------
// A-fragment producer (dedup): wave cg computes ONLY its quarter of the
// shared score fragment: k = {2cg, 2cg+1} (dword j=cg) and {2cg+8, 2cg+9}
// (dword j=cg+4), does cvt_pk + permlane32_swap, publishes POST-SWAP dwords
// to the LDS A-plane. Consumers rebuild a0 = dwords 0..3, a1 = dwords 4..7.
// Layout ab[pair = j>>1][lane][slot = j&1] -> b64 reads, conflict-free.
// ---------------------------------------------------------------------------
static __device__ __forceinline__ void produceA(
    const float* __restrict__ kpq,
    float qx, float qy, float qz, float qw,
    int l, int cg, unsigned int (*ab)[64][2])
{
    float2 a0 = *(const float2*)(kpq);
    float2 a1 = *(const float2*)(kpq + 2);
    float2 a2 = *(const float2*)(kpq + 4);
    float2 b0 = *(const float2*)(kpq + 24);
    float2 b1 = *(const float2*)(kpq + 26);
    float2 b2 = *(const float2*)(kpq + 28);
    float e0 = EXP2F(fmaf(qx, a0.x, fmaf(qy, a0.y, fmaf(qz, a1.x, qw))));
    float e1 = EXP2F(fmaf(qx, a1.y, fmaf(qy, a2.x, fmaf(qz, a2.y, qw))));
    float e2 = EXP2F(fmaf(qx, b0.x, fmaf(qy, b0.y, fmaf(qz, b1.x, qw))));
    float e3 = EXP2F(fmaf(qx, b1.y, fmaf(qy, b2.x, fmaf(qz, b2.y, qw))));
    unsigned int d0, d1;
    asm("v_cvt_pk_bf16_f32 %0, %1, %2" : "=v"(d0) : "v"(e0), "v"(e1));
    asm("v_cvt_pk_bf16_f32 %0, %1, %2" : "=v"(d1) : "v"(e2), "v"(e3));
    asm("v_permlane32_swap_b32 %0, %1" : "+v"(d0), "+v"(d1));
    ab[cg >> 1][l][cg & 1]       = d0;
    ab[(cg >> 1) + 2][l][cg & 1] = d1;
}

// ---------------------------------------------------------------------------
// Kernel 3 (main): 512 blocks = 4 b x 32 qt x 4 nf-splits, 256 threads
// (4 waves = 4 c-groups). Block: 64 q x FULL 768 c x 4096 k. Each wave:
// 2 q-subtiles x 6 c-subtiles of 32x32x16 MFMA. A-fragments computed ONCE
// per block (quarter per wave) and shared via LDS (4x less score VALU).
// 52 KB LDS -> 2 independent blocks/CU: one block's barrier/drain stalls
// hide under the other's compute (TLP instead of fragile counted-vmcnt).
// ---------------------------------------------------------------------------
__global__ __launch_bounds__(256, 2) void attn_main32_kernel(
    const char* __restrict__ vpk, const float4* __restrict__ qp,
    const float* __restrict__ kp3, float* __restrict__ out,
    float* __restrict__ partial)
{
    __shared__ __align__(16) char vbuf[2][TILEB];          // 2 x 24 KiB
    __shared__ __align__(16) unsigned int abuf[2][4][64][2]; // 2 x 2 KiB

    const int t   = threadIdx.x;
    const int l   = t & 63;
    const int cg  = t >> 6;           // wave = c-group 0..3 (192 cols each)

    const int bid = blockIdx.x;
    // XCD swizzle: all 32 qt-blocks of one (b,nfs) slab land on one XCD
    const int g   = ((bid & 7) << 1) | ((bid >> 3) & 1);  // 0..15 -> (b, nfs)
    const int qt  = bid >> 4;                             // 0..31
    const int b   = g >> 2;
    const int nfs = g & 3;

    const char*  vtile = vpk + (size_t)(b * (NF / BK2) + nfs * NCH2) * TILEB;
    const float* kpb   = kp3 + (size_t)(b * NF + nfs * KC) * 3;

    // lane l owns q-row qt*64 + l (same for ALL waves -> dedup works).
    const float4 qv = qp[b * NQ + qt * 64 + l];
    const float qx = qv.x, qy = qv.y, qz = qv.z, qw = qv.w;

    floatx16 acc0[6], acc1[6];
#pragma unroll
    for (int cs = 0; cs < 6; ++cs)
#pragma unroll
        for (int r = 0; r < 16; ++r) { acc0[cs][r] = 0.0f; acc1[cs][r] = 0.0f; }

    const int lhi  = l >> 5;
    // B-read: col c = cg*192 + cs*32 + (l&31); byte = c*32 + slot*16,
    // slot = lhi ^ ((c>>2)&1) = lhi ^ ((l>>2)&1)  (cs*32, cg*192 are even in bit2)
    const int bofs = (cg * 192 + (l & 31)) * 32 + ((lhi ^ ((l >> 2) & 1)) << 4);

#define STAGE(CH, PB)                                                         \
    do {                                                                      \
        const char* src = vtile + (size_t)(CH) * TILEB + cg * 6144 + l * 16;  \
        char* dst = &vbuf[PB][cg * 6144];                                     \
        _Pragma("unroll")                                                     \
        for (int i = 0; i < 6; ++i) GLDS16(src + i * 1024, dst + i * 1024);   \
    } while (0)

    // ---- prologue: stage chunk 0, produce A(0) ----
    STAGE(0, 0);
    produceA(kpb + 6 * cg, qx, qy, qz, qw, l, cg, abuf[0]);

#pragma unroll 1
    for (int ch = 0; ch < NCH2; ++ch) {
        // publish abuf writes + own B-reads done; DMA(ch) landed
        asm volatile("s_waitcnt vmcnt(0) lgkmcnt(0)" ::: "memory");
        __builtin_amdgcn_sched_barrier(0);
        __builtin_amdgcn_s_barrier();
        __builtin_amdgcn_sched_barrier(0);

        const int cur = ch & 1, nxt = cur ^ 1;
        if (ch + 1 < NCH2) STAGE(ch + 1, nxt);

        // A-fragments for this chunk (shared, produced last epoch)
        union { unsigned int u[4]; short8 s; } a0, a1;
        {
            const unsigned int (*AB)[64][2] = abuf[cur];
            uint2 p0 = *(const uint2*)&AB[0][l][0];
            uint2 p1 = *(const uint2*)&AB[1][l][0];
            uint2 p2 = *(const uint2*)&AB[2][l][0];
            uint2 p3 = *(const uint2*)&AB[3][l][0];
            a0.u[0] = p0.x; a0.u[1] = p0.y; a0.u[2] = p1.x; a0.u[3] = p1.y;
            a1.u[0] = p2.x; a1.u[1] = p2.y; a1.u[2] = p3.x; a1.u[3] = p3.y;
        }

        const char* bp = &vbuf[cur][0] + bofs;
        __builtin_amdgcn_s_setprio(1);
#pragma unroll
        for (int cs = 0; cs < 6; ++cs) {
            union { uint4 u; short8 s; } bw;
            bw.u = *(const uint4*)(bp + cs * 1024);
            acc0[cs] = __builtin_amdgcn_mfma_f32_32x32x16_bf16(a0.s, bw.s, acc0[cs], 0, 0, 0);
            acc1[cs] = __builtin_amdgcn_mfma_f32_32x32x16_bf16(a1.s, bw.s, acc1[cs], 0, 0, 0);
        }
        __builtin_amdgcn_s_setprio(0);

        // produce A(ch+1) (quarter per wave; kp latency hides under MFMA)
        if (ch + 1 < NCH2)
            produceA(kpb + (size_t)(ch + 1) * (BK2 * 3) + 6 * cg,
                     qx, qy, qz, qw, l, cg, abuf[nxt]);
    }
#undef STAGE

    // ---- epilogue: raw partial sums (split 0 -> out, splits 1..3 -> ws) ----
    float* obase = (nfs == 0) ? out
                 : (partial + (size_t)(nfs - 1) * ((size_t)Bt * NQ * CC));
    const int row0 = b * NQ + qt * 64 + 4 * lhi;
    const int col0 = cg * 192 + (l & 31);
#pragma unroll
    for (int cs = 0; cs < 6; ++cs)
#pragma unroll
        for (int r = 0; r < 16; ++r) {
            const int row = row0 + (r & 3) + 8 * (r >> 2);
            obase[(size_t)row * CC + col0 + cs * 32]        = acc0[cs][r];
            obase[(size_t)(row + 32) * CC + col0 + cs * 32] = acc1[cs][r];
        }
}

// ---------------------------------------------------------------------------
// Kernel 4 (reduce): out = (out + p1 + p2 + p3) * (1/l)
// ---------------------------------------------------------------------------
__global__ __launch_bounds__(256) void reduce_kernel(
    float* __restrict__ out, const float* __restrict__ part,
    const float2* __restrict__ rstat)
{
    const int TOT4 = Bt * NQ * CC / 4;     // 1,572,864
    float4* o4 = (float4*)out;
    const float4* p4 = (const float4*)part;
    for (int i = blockIdx.x * 256 + threadIdx.x; i < TOT4; i += gridDim.x * 256) {
        float4 o = o4[i];
        float4 a = p4[i], b2 = p4[TOT4 + i], c2 = p4[2 * TOT4 + i];
        float lv = rstat[i / (CC / 4)].y;
        o.x = (o.x + a.x + b2.x + c2.x) * lv;
        o.y = (o.y + a.y + b2.y + c2.y) * lv;
        o.z = (o.z + a.z + b2.z + c2.z) * lv;
        o.w = (o.w + a.w + b2.w + c2.w) * lv;
        o4[i] = o;
    }
}

// ---------------------------------------------------------------------------
// FALLBACK (old main kernel, known-good): used only if ws_size is too small
// for the bf16 v-prepack + partial buffers. Reads raw v directly.
// ---------------------------------------------------------------------------
__global__ __launch_bounds__(THR, 4) void attn_mfma_kernel(
    const float* __restrict__ v, const float4* __restrict__ qp,
    const float* __restrict__ kp3, const float2* __restrict__ rstat,
    float* __restrict__ out)
{
    __shared__ unsigned int vTd[2][CT * 68];
    __shared__ float4 kplB[2][96];

    const int t    = threadIdx.x;
    const int bid  = blockIdx.x;
    const int g    = (bid & 7) + 8 * ((bid >> 3) & 3);
    const int qt   = bid >> 5;
    const int b    = g >> 3;
    const int ct   = g & 7;

    const int lane = t & 63;
    const int wv   = t >> 6;
    const int quad = lane >> 4;
    const int l15  = lane & 15;

    const int qrow0 = b * NQ + qt * QT;
    const int cbase = ct * CT;

    float4 qv = qp[qrow0 + wv * 16 + l15];
    const float qx = qv.x, qy = qv.y, qz = qv.z, qw = qv.w;

    const int rp  = (t & 7) + 8 * wv;
    const int c4l = (t >> 3) & 7;

    const float*  vb   = v + (size_t)b * NF * CC + cbase;
    const float4* kp4g = (const float4*)(kp3 + (size_t)b * NF * 3);

    floatx4 acc[6];
#pragma unroll
    for (int cs = 0; cs < 6; ++cs) acc[cs] = (floatx4){0.f, 0.f, 0.f, 0.f};

    float va0[3][4], va1[3][4];
    float4 kpld = make_float4(0.f, 0.f, 0.f, 0.f);

#pragma unroll
    for (int rep = 0; rep < 3; ++rep) {
        int col = 4 * (c4l + 8 * rep);
        const float4* p0 = (const float4*)(vb + (size_t)(2 * rp) * CC + col);
        float4 a = p0[0];
        float4 bq = p0[CC / 4];
        va0[rep][0] = a.x;  va0[rep][1] = a.y;  va0[rep][2] = a.z;  va0[rep][3] = a.w;
        va1[rep][0] = bq.x; va1[rep][1] = bq.y; va1[rep][2] = bq.z; va1[rep][3] = bq.w;
    }
    if (t < 96) kpld = kp4g[t];

    for (int ch = 0; ch < NCH; ++ch) {
        const int p = ch & 1;
#pragma unroll
        for (int rep = 0; rep < 3; ++rep) {
            int c0 = 4 * (c4l + 8 * rep);
#pragma unroll
            for (int w = 0; w < 4; ++w) {
                unsigned int pk = f2bf(va0[rep][w]) | (f2bf(va1[rep][w]) << 16);
                vTd[p][(c0 + w) * 68 + (rp ^ (4 * c4l))] = pk;
            }
        }
        if (t < 96) kplB[p][t] = kpld;
        __syncthreads();

        if (ch + 1 < NCH) {
            int m0 = (ch + 1) * BK;
#pragma unroll
            for (int rep = 0; rep < 3; ++rep) {
                int col = 4 * (c4l + 8 * rep);
                const float4* p0 = (const float4*)(vb + (size_t)(m0 + 2 * rp) * CC + col);
                float4 a = p0[0];
                float4 bq = p0[CC / 4];
                va0[rep][0] = a.x;  va0[rep][1] = a.y;  va0[rep][2] = a.z;  va0[rep][3] = a.w;
                va1[rep][0] = bq.x; va1[rep][1] = bq.y; va1[rep][2] = bq.z; va1[rep][3] = bq.w;
            }
            if (t < 96) kpld = kp4g[(ch + 1) * 96 + t];
        }

#pragma unroll
        for (int kk = 0; kk < BK; kk += 32) {
            union { float4 v4[6]; float f[24]; } kq;
            const int kb4 = (kk * 3) / 4 + 6 * quad;
#pragma unroll
            for (int i = 0; i < 6; ++i) kq.v4[i] = kplB[p][kb4 + i];

            union { short8 s; unsigned int d[4]; } af;
#pragma unroll
            for (int j = 0; j < 8; j += 2) {
                float s0 = fmaf(qx, kq.f[3 * j],
                           fmaf(qy, kq.f[3 * j + 1],
                           fmaf(qz, kq.f[3 * j + 2], qw)));
                float s1 = fmaf(qx, kq.f[3 * j + 3],
                           fmaf(qy, kq.f[3 * j + 4],
                           fmaf(qz, kq.f[3 * j + 5], qw)));
                af.d[j >> 1] = f2bf(EXP2F(s0)) | (f2bf(EXP2F(s1)) << 16);
            }

#pragma unroll
            for (int cs = 0; cs < 6; ++cs) {
                int c  = cs * 16 + l15;
                int d0 = ((kk >> 1) + 4 * quad) ^ (4 * ((c >> 2) & 7));
                union { uint4 u; short8 s; } bw;
                bw.u = *(const uint4*)&vTd[p][c * 68 + d0];
                acc[cs] = __builtin_amdgcn_mfma_f32_16x16x32_bf16(
                    af.s, bw.s, acc[cs], 0, 0, 0);
            }
        }
        __syncthreads();
    }

#pragma unroll
    for (int vv = 0; vv < 4; ++vv) {
        int row = qrow0 + wv * 16 + quad * 4 + vv;
        float lv = rstat[row].y;
        float* orow = out + (size_t)row * CC + cbase + l15;
#pragma unroll
        for (int cs = 0; cs < 6; ++cs)
            orow[cs * 16] = acc[cs][vv] * lv;
    }
}

// ---------------------------------------------------------------------------
extern "C" void kernel_launch(void* const* d_in, const int* in_sizes, int n_in,
                              void* d_out, int out_size, void* d_ws, size_t ws_size,
                              hipStream_t stream) {
    const float* q  = (const float*)d_in[0];
    const float* k  = (const float*)d_in[1];
    const float* v  = (const float*)d_in[2];
    const float* W1 = (const float*)d_in[3];
    const float* b1 = (const float*)d_in[4];
    const float* W2 = (const float*)d_in[5];
    const float* b2 = (const float*)d_in[6];
    float* out = (float*)d_out;

    // ws layout: kp3 (768K) | qp (128K) | rstat (64K) | vpk (96M) | partials (72M)
    float*  kp3   = (float*)d_ws;
    float4* qpW   = (float4*)((char*)d_ws + (size_t)Bt * NF * 3 * 4);
    float2* rstat = (float2*)((char*)d_ws + (size_t)Bt * NF * 3 * 4 + (size_t)Bt * NQ * 16);
    char*   vpk   = (char*)d_ws + 983040;
    float*  part  = (float*)((char*)d_ws + 983040 + (size_t)NTILE * TILEB);
    const size_t need = 983040 + (size_t)NTILE * TILEB
                      + (size_t)3 * Bt * NQ * CC * 4;   // ~177.1 MB

    hipLaunchKernelGGL(prep_kernel, dim3((Bt * NQ + Bt * NF) / 256), dim3(256), 0, stream,
                       q, k, W1, b1, W2, b2, qpW, kp3);
    hipLaunchKernelGGL(stats_kernel, dim3(Bt * (NQ / 16)), dim3(256), 0, stream,
                       qpW, kp3, rstat);

    if (ws_size >= need) {
        hipLaunchKernelGGL(prep_v_kernel, dim3(Bt * (NF / BK2) * 6), dim3(256), 0, stream,
                           v, vpk);
        hipLaunchKernelGGL(attn_main32_kernel, dim3(Bt * 32 * NFS), dim3(256), 0, stream,
                           vpk, qpW, kp3, out, part);
        hipLaunchKernelGGL(reduce_kernel, dim3(2048), dim3(256), 0, stream,
                           out, part, rstat);
    } else {
        // workspace too small for prepack+partials: proven fallback path
        hipLaunchKernelGGL(attn_mfma_kernel, dim3(Bt * (NQ / QT) * (CC / CT)), dim3(THR), 0, stream,
                           v, qpW, kp3, rstat, out);
    }
}

// Round 5
// 656.500 us; speedup vs baseline: 1.1323x; 1.1323x over previous
//
#include <hip/hip_runtime.h>
#include <math.h>

// Problem constants: B=4, Nq=2048, Nf=16384, D=3, C=768
#define Bt  4
#define NQ  2048
#define NF  16384
#define CC  768

// ---- old-path (fallback) tile params ----
#define QT  128     // q-rows per old main block
#define CT  96      // channels per old main block
#define BK  128     // Nf chunk per LDS stage (old)
#define THR 512     // threads per old main block
#define NCH (NF / BK)

// ---- new-path params ----
#define NFS   4                  // Nf splits (partial sums)
#define KC    (NF / NFS)         // 4096 k per block
#define BK2   32                 // k per LDS chunk
#define NCH2  (KC / BK2)         // 128 chunks per block
#define TILEB (CC * BK2 * 2)     // 49152 B per bf16 v-tile (one chunk, all 768 c)
#define NTILE (Bt * (NF / BK2))  // 2048 tiles total (96 MB)

#define SCALE_LOG2E 0.8329080161227079f   // (1/sqrt(3)) * log2(e)

typedef __attribute__((ext_vector_type(8)))  short  short8;
typedef __attribute__((ext_vector_type(4)))  float  floatx4;
typedef __attribute__((ext_vector_type(16))) float  floatx16;

#if __has_builtin(__builtin_amdgcn_exp2f)
#define EXP2F(x) __builtin_amdgcn_exp2f(x)
#else
#define EXP2F(x) __expf((x) * 0.6931471805599453f)
#endif

static __device__ __forceinline__ float relu(float x) { return fmaxf(x, 0.0f); }

// fp32 -> bf16 bits, round-to-nearest-even (inputs finite, non-NaN)
static __device__ __forceinline__ unsigned int f2bf(float f) {
    unsigned int u = __float_as_uint(f);
    u += 0x7fffu + ((u >> 16) & 1u);
    return u >> 16;
}

// direct-to-LDS 16B DMA (linear dest: wave-uniform base + lane*16)
#define GLDS16(gsrc, ldst)                                                        \
    __builtin_amdgcn_global_load_lds(                                             \
        (const __attribute__((address_space(1))) unsigned int*)(gsrc),            \
        (__attribute__((address_space(3))) unsigned int*)(ldst), 16, 0, 0)

// ---------------------------------------------------------------------------
// Kernel 1 (prep): qp = relu(q@W1^T+b1)*SCALE*log2e (float4, w=0 placeholder)
//                  kp = relu(k@W2^T+b2) stored TIGHT float3
// ---------------------------------------------------------------------------
__global__ __launch_bounds__(256) void prep_kernel(
    const float* __restrict__ q, const float* __restrict__ k,
    const float* __restrict__ W1, const float* __restrict__ b1,
    const float* __restrict__ W2, const float* __restrict__ b2,
    float4* __restrict__ qp, float* __restrict__ kp3)
{
    int idx = blockIdx.x * 256 + threadIdx.x;
    if (idx < Bt * NQ) {
        const float* r = q + (size_t)idx * 3;
        float x0 = r[0], x1 = r[1], x2 = r[2];
        float4 o;
        o.x = relu(fmaf(W1[0], x0, fmaf(W1[1], x1, fmaf(W1[2], x2, b1[0])))) * SCALE_LOG2E;
        o.y = relu(fmaf(W1[3], x0, fmaf(W1[4], x1, fmaf(W1[5], x2, b1[1])))) * SCALE_LOG2E;
        o.z = relu(fmaf(W1[6], x0, fmaf(W1[7], x1, fmaf(W1[8], x2, b1[2])))) * SCALE_LOG2E;
        o.w = 0.0f;
        qp[idx] = o;
    } else {
        int kidx = idx - Bt * NQ;   // < Bt*NF by grid construction
        const float* r = k + (size_t)kidx * 3;
        float x0 = r[0], x1 = r[1], x2 = r[2];
        float* dst = kp3 + (size_t)kidx * 3;
        dst[0] = relu(fmaf(W2[0], x0, fmaf(W2[1], x1, fmaf(W2[2], x2, b2[0]))));
        dst[1] = relu(fmaf(W2[3], x0, fmaf(W2[4], x1, fmaf(W2[5], x2, b2[1]))));
        dst[2] = relu(fmaf(W2[6], x0, fmaf(W2[7], x1, fmaf(W2[8], x2, b2[2]))));
    }
}

// ---------------------------------------------------------------------------
// Kernel 2 (stats): rowmax' (log2 domain) and 1/sum(exp2). Writes qp.w = -rm.
// kp loads vectorized: 3 x float4 = 4 k-points per iter (4x fewer load insts).
// ---------------------------------------------------------------------------
__global__ __launch_bounds__(256) void stats_kernel(
    float4* __restrict__ qp, const float* __restrict__ kp3,
    float2* __restrict__ rstat)
{
    __shared__ float wredA[4][16];
    __shared__ float wredB[4][16];

    const int bid  = blockIdx.x;
    const int b    = bid >> 7;            // NQ/16 = 128 blocks per batch
    const int q0   = (bid & 127) * 16;
    const int t    = threadIdx.x;
    const int wv   = t >> 6;
    const int lane = t & 63;

    float qx[16], qy[16], qz[16];
#pragma unroll
    for (int i = 0; i < 16; ++i) {
        float4 qv = qp[b * NQ + q0 + i];
        qx[i] = qv.x; qy[i] = qv.y; qz[i] = qv.z;
    }
    const float4* kp4 = (const float4*)(kp3 + (size_t)b * NF * 3);

    float pmax[16];
#pragma unroll
    for (int i = 0; i < 16; ++i) pmax[i] = -1e30f;
    for (int m4 = t; m4 < NF / 4; m4 += 256) {
        float4 A = kp4[3 * m4], B4 = kp4[3 * m4 + 1], C4 = kp4[3 * m4 + 2];
#pragma unroll
        for (int i = 0; i < 16; ++i) {
            float s0 = fmaf(qx[i], A.x,  fmaf(qy[i], A.y,  qz[i] * A.z));
            float s1 = fmaf(qx[i], A.w,  fmaf(qy[i], B4.x, qz[i] * B4.y));
            float s2 = fmaf(qx[i], B4.z, fmaf(qy[i], B4.w, qz[i] * C4.x));
            float s3 = fmaf(qx[i], C4.y, fmaf(qy[i], C4.z, qz[i] * C4.w));
            pmax[i] = fmaxf(pmax[i], fmaxf(fmaxf(s0, s1), fmaxf(s2, s3)));
        }
    }
#pragma unroll
    for (int off = 32; off >= 1; off >>= 1)
#pragma unroll
        for (int i = 0; i < 16; ++i)
            pmax[i] = fmaxf(pmax[i], __shfl_xor(pmax[i], off, 64));
    if (lane == 0)
#pragma unroll
        for (int i = 0; i < 16; ++i) wredA[wv][i] = pmax[i];
    __syncthreads();

    float rowmax[16];
#pragma unroll
    for (int i = 0; i < 16; ++i)
        rowmax[i] = fmaxf(fmaxf(wredA[0][i], wredA[1][i]),
                          fmaxf(wredA[2][i], wredA[3][i]));

    float psum[16];
#pragma unroll
    for (int i = 0; i < 16; ++i) psum[i] = 0.0f;
    for (int m4 = t; m4 < NF / 4; m4 += 256) {
        float4 A = kp4[3 * m4], B4 = kp4[3 * m4 + 1], C4 = kp4[3 * m4 + 2];
#pragma unroll
        for (int i = 0; i < 16; ++i) {
            float s0 = fmaf(qx[i], A.x,  fmaf(qy[i], A.y,  qz[i] * A.z));
            float s1 = fmaf(qx[i], A.w,  fmaf(qy[i], B4.x, qz[i] * B4.y));
            float s2 = fmaf(qx[i], B4.z, fmaf(qy[i], B4.w, qz[i] * C4.x));
            float s3 = fmaf(qx[i], C4.y, fmaf(qy[i], C4.z, qz[i] * C4.w));
            psum[i] += EXP2F(s0 - rowmax[i]) + EXP2F(s1 - rowmax[i])
                     + EXP2F(s2 - rowmax[i]) + EXP2F(s3 - rowmax[i]);
        }
    }
#pragma unroll
    for (int off = 32; off >= 1; off >>= 1)
#pragma unroll
        for (int i = 0; i < 16; ++i)
            psum[i] += __shfl_xor(psum[i], off, 64);
    if (lane == 0)
#pragma unroll
        for (int i = 0; i < 16; ++i) wredB[wv][i] = psum[i];
    __syncthreads();

    if (t < 16) {
        float m = fmaxf(fmaxf(wredA[0][t], wredA[1][t]),
                        fmaxf(wredA[2][t], wredA[3][t]));
        float l = wredB[0][t] + wredB[1][t] + wredB[2][t] + wredB[3][t];
        int row = b * NQ + q0 + t;
        rstat[row] = make_float2(m, 1.0f / l);
        qp[row].w = -m;
    }
}

// ---------------------------------------------------------------------------
// Kernel 2b (prep_v): v f32 -> bf16 in the swizzled B-fragment tile layout
// for BK2=32 chunks (round-2 version, hardware-validated).
// Tile (b, ch): byte(c,k) = c*64 + slot*16 + (k&7)*2,
//   slot = (k>>3) ^ (((c>>1) ^ (c>>3)) & 3)
// ---------------------------------------------------------------------------
__global__ __launch_bounds__(256) void prep_v_kernel(
    const float* __restrict__ v, char* __restrict__ vpk)
{
    __shared__ float lt[32][68];          // 32 k-rows x 64 c (+4 pad)
    const int t   = threadIdx.x;
    const int bid = blockIdx.x;           // Bt * 512 * 12 blocks
    const int cb  = bid % 12;
    const int ch  = (bid / 12) & 511;
    const int b   = bid / (12 * 512);
    const int c0  = cb * 64;

    // load 32 k x 64 c f32 tile, coalesced
    const float* vb = v + ((size_t)b * NF + (size_t)ch * BK2) * CC + c0;
    const int mi = t >> 4, c4 = (t & 15) << 2;
#pragma unroll
    for (int r2 = 0; r2 < 2; ++r2) {
        const int m = mi + 16 * r2;
        *(float4*)&lt[m][c4] = *(const float4*)(vb + (size_t)m * CC + c4);
    }
    __syncthreads();

    // each thread emits one 16B slot: c = t>>2 (local), logical slot = t&3 (8 k's)
    const int c  = t >> 2;
    const int sl = t & 3;
    unsigned int dw[4];
#pragma unroll
    for (int i = 0; i < 4; ++i) {
        float a  = lt[8 * sl + 2 * i][c];
        float b2 = lt[8 * sl + 2 * i + 1][c];
        asm("v_cvt_pk_bf16_f32 %0, %1, %2" : "=v"(dw[i]) : "v"(a), "v"(b2));
    }
    const int cgl = c0 + c;
    char* dst = vpk + (size_t)(b * 512 + ch) * TILEB
              + ((size_t)cgl << 6)
              + ((sl ^ (((cgl >> 1) ^ (cgl >> 3)) & 3)) << 4);
    uint4 u; u.x = dw[0]; u.y = dw[1]; u.z = dw[2]; u.w = dw[3];
    *(uint4*)dst = u;
}

// ---------------------------------------------------------------------------
// Kernel 3 (main): 256 blocks = 4b x 16qt x 4nfs, 512 threads (8 waves =
// 2 q-groups x 4 c-groups). Block: 128 q x 768 c x 4096 k, BK2=32 chunks,
// NBUF=2. A-fragments deduplicated: each of the 8 waves produces exactly
// one (wg,cg)-quarter of the shared score fragments into a double-buffered
// LDS A-plane (round-4-validated produceA math, extended by wg plane).
// T14 on kp: the 12 uniform float2 loads for chunk ch+1 are issued at the
// TOP of iter ch (with the DMAs) and consumed at the bottom -> vmcnt(0)
// at the barrier is a free drain (everything had a full chunk to land).
// ---------------------------------------------------------------------------
__global__ __launch_bounds__(512) void attn_main32_kernel(
    const char* __restrict__ vpk, const float4* __restrict__ qp,
    const float* __restrict__ kp3, float* __restrict__ out,
    float* __restrict__ partial)
{
    __shared__ __align__(16) char vbuf[2][TILEB];                   // 96 KiB
    __shared__ __align__(16) unsigned int abuf[2][2][2][4][64][2];  // 16 KiB
    // abuf dims: [buf][kk][wg][pair][lane][slot]

    const int t  = threadIdx.x;
    const int l  = t & 63;
    const int wv = t >> 6;
    const int wg = wv >> 2;          // q-group 0..1 (64 rows each)
    const int cg = wv & 3;           // c-group 0..3 (192 cols each)

    const int bid = blockIdx.x;
    // XCD swizzle: all 16 qt-blocks of one (b,nfs) slab land on one XCD
    const int g   = ((bid & 7) << 1) | ((bid >> 3) & 1);  // 0..15 -> (b, nfs)
    const int qt  = bid >> 4;                             // 0..15
    const int b   = g >> 2;
    const int nfs = g & 3;

    const char*  vtile = vpk + (size_t)(b * (NF / BK2) + nfs * NCH2) * TILEB;
    const float* kpb   = kp3 + (size_t)(b * NF + nfs * KC) * 3;

    // lane l owns q-row qt*128 + wg*64 + l. qp.w already = -rowmax (log2).
    const float4 qv = qp[b * NQ + qt * QT + wg * 64 + l];
    const float qx = qv.x, qy = qv.y, qz = qv.z, qw = qv.w;

    floatx16 acc0[6], acc1[6];
#pragma unroll
    for (int cs = 0; cs < 6; ++cs)
#pragma unroll
        for (int r = 0; r < 16; ++r) { acc0[cs][r] = 0.0f; acc1[cs][r] = 0.0f; }

    const int lhi  = l >> 5;
    const int swzl = ((l >> 1) ^ (l >> 3)) & 3;          // matches prep_v slot XOR
    const int bofs = (cg * 192 + (l & 31)) * 64;         // c*64; +cs*2048 via imm

#define STAGE(CH, PB)                                                         \
    do {                                                                      \
        const char* src = vtile + (size_t)(CH) * TILEB + wv * 1024 + l * 16;  \
        char* dst = &vbuf[PB][wv * 1024];                                     \
        _Pragma("unroll")                                                     \
        for (int i = 0; i < 6; ++i) GLDS16(src + i * 8192, dst + i * 8192);   \
    } while (0)

    // 12 uniform float2 loads: kk 0/1 x (k = 2cg,2cg+1 then 2cg+8,2cg+9)
#define KPLOAD(CH, R)                                                         \
    do {                                                                      \
        const float* base_ = kpb + (size_t)(CH) * (BK2 * 3) + 6 * cg;         \
        _Pragma("unroll")                                                     \
        for (int kk_ = 0; kk_ < 2; ++kk_) {                                   \
            const float* p_ = base_ + kk_ * 48;                               \
            R[kk_ * 6 + 0] = *(const float2*)(p_);                            \
            R[kk_ * 6 + 1] = *(const float2*)(p_ + 2);                        \
            R[kk_ * 6 + 2] = *(const float2*)(p_ + 4);                        \
            R[kk_ * 6 + 3] = *(const float2*)(p_ + 24);                       \
            R[kk_ * 6 + 4] = *(const float2*)(p_ + 26);                       \
            R[kk_ * 6 + 5] = *(const float2*)(p_ + 28);                       \
        }                                                                     \
    } while (0)

    // produce this wave's (wg,cg) quarter for one kk into abuf[BB][KK]
#define PRODA(R, O, BB, KK)                                                   \
    do {                                                                      \
        float e0_ = EXP2F(fmaf(qx, R[O+0].x, fmaf(qy, R[O+0].y, fmaf(qz, R[O+1].x, qw)))); \
        float e1_ = EXP2F(fmaf(qx, R[O+1].y, fmaf(qy, R[O+2].x, fmaf(qz, R[O+2].y, qw)))); \
        float e2_ = EXP2F(fmaf(qx, R[O+3].x, fmaf(qy, R[O+3].y, fmaf(qz, R[O+4].x, qw)))); \
        float e3_ = EXP2F(fmaf(qx, R[O+4].y, fmaf(qy, R[O+5].x, fmaf(qz, R[O+5].y, qw)))); \
        unsigned int d0_, d1_;                                                \
        asm("v_cvt_pk_bf16_f32 %0, %1, %2" : "=v"(d0_) : "v"(e0_), "v"(e1_)); \
        asm("v_cvt_pk_bf16_f32 %0, %1, %2" : "=v"(d1_) : "v"(e2_), "v"(e3_)); \
        asm("v_permlane32_swap_b32 %0, %1" : "+v"(d0_), "+v"(d1_));           \
        abuf[BB][KK][wg][cg >> 1][l][cg & 1]       = d0_;                     \
        abuf[BB][KK][wg][(cg >> 1) + 2][l][cg & 1] = d1_;                     \
    } while (0)

    // ---- prologue: stage chunk 0, produce A(0) ----
    {
        float2 kpr[12];
        KPLOAD(0, kpr);
        STAGE(0, 0);
        PRODA(kpr, 0, 0, 0);
        PRODA(kpr, 6, 0, 1);
    }

#pragma unroll 1
    for (int ch = 0; ch < NCH2; ++ch) {
        // everything in flight (DMA ch, kp ch) had a full chunk to land
        asm volatile("s_waitcnt vmcnt(0) lgkmcnt(0)" ::: "memory");
        __builtin_amdgcn_sched_barrier(0);
        __builtin_amdgcn_s_barrier();
        __builtin_amdgcn_sched_barrier(0);

        const int cur = ch & 1, nxt = cur ^ 1;
        float2 kpn[12];
        if (ch + 1 < NCH2) {
            STAGE(ch + 1, nxt);       // issue early (T14)
            KPLOAD(ch + 1, kpn);      // issue early (T14)
        }
        __builtin_amdgcn_sched_barrier(0);

#pragma unroll
        for (int kk = 0; kk < 2; ++kk) {
            union { unsigned int u[4]; short8 s; } a0, a1;
            {
                uint2 p0 = *(const uint2*)&abuf[cur][kk][wg][0][l][0];
                uint2 p1 = *(const uint2*)&abuf[cur][kk][wg][1][l][0];
                uint2 p2 = *(const uint2*)&abuf[cur][kk][wg][2][l][0];
                uint2 p3 = *(const uint2*)&abuf[cur][kk][wg][3][l][0];
                a0.u[0] = p0.x; a0.u[1] = p0.y; a0.u[2] = p1.x; a0.u[3] = p1.y;
                a1.u[0] = p2.x; a1.u[1] = p2.y; a1.u[2] = p3.x; a1.u[3] = p3.y;
            }
            const char* bp = &vbuf[cur][0] + bofs + (((2 * kk + lhi) ^ swzl) << 4);

            __builtin_amdgcn_s_setprio(1);
#pragma unroll
            for (int cs = 0; cs < 6; ++cs) {
                union { uint4 u; short8 s; } bw;
                bw.u = *(const uint4*)(bp + cs * 2048);
                acc0[cs] = __builtin_amdgcn_mfma_f32_32x32x16_bf16(a0.s, bw.s, acc0[cs], 0, 0, 0);
                acc1[cs] = __builtin_amdgcn_mfma_f32_32x32x16_bf16(a1.s, bw.s, acc1[cs], 0, 0, 0);
            }
            __builtin_amdgcn_s_setprio(0);
        }

        // consume late: A(ch+1) from the registers loaded at the top
        if (ch + 1 < NCH2) {
            PRODA(kpn, 0, nxt, 0);
            PRODA(kpn, 6, nxt, 1);
        }
    }
#undef STAGE
#undef KPLOAD
#undef PRODA

    // ---- epilogue: raw partial sums (split 0 -> out, splits 1..3 -> ws) ----
    float* obase = (nfs == 0) ? out
                 : (partial + (size_t)(nfs - 1) * ((size_t)Bt * NQ * CC));
    const int row0 = b * NQ + qt * QT + wg * 64 + 4 * lhi;
    const int col0 = cg * 192 + (l & 31);
#pragma unroll
    for (int cs = 0; cs < 6; ++cs)
#pragma unroll
        for (int r = 0; r < 16; ++r) {
            const int row = row0 + (r & 3) + 8 * (r >> 2);
            obase[(size_t)row * CC + col0 + cs * 32]        = acc0[cs][r];
            obase[(size_t)(row + 32) * CC + col0 + cs * 32] = acc1[cs][r];
        }
}

// ---------------------------------------------------------------------------
// Kernel 4 (reduce): out = (out + p1 + p2 + p3) * (1/l)
// ---------------------------------------------------------------------------
__global__ __launch_bounds__(256) void reduce_kernel(
    float* __restrict__ out, const float* __restrict__ part,
    const float2* __restrict__ rstat)
{
    const int TOT4 = Bt * NQ * CC / 4;     // 1,572,864
    float4* o4 = (float4*)out;
    const float4* p4 = (const float4*)part;
    for (int i = blockIdx.x * 256 + threadIdx.x; i < TOT4; i += gridDim.x * 256) {
        float4 o = o4[i];
        float4 a = p4[i], b2 = p4[TOT4 + i], c2 = p4[2 * TOT4 + i];
        float lv = rstat[i / (CC / 4)].y;
        o.x = (o.x + a.x + b2.x + c2.x) * lv;
        o.y = (o.y + a.y + b2.y + c2.y) * lv;
        o.z = (o.z + a.z + b2.z + c2.z) * lv;
        o.w = (o.w + a.w + b2.w + c2.w) * lv;
        o4[i] = o;
    }
}

// ---------------------------------------------------------------------------
// FALLBACK (old main kernel, known-good): used only if ws_size is too small
// for the bf16 v-prepack + partial buffers. Reads raw v directly.
// ---------------------------------------------------------------------------
__global__ __launch_bounds__(THR, 4) void attn_mfma_kernel(
    const float* __restrict__ v, const float4* __restrict__ qp,
    const float* __restrict__ kp3, const float2* __restrict__ rstat,
    float* __restrict__ out)
{
    __shared__ unsigned int vTd[2][CT * 68];
    __shared__ float4 kplB[2][96];

    const int t    = threadIdx.x;
    const int bid  = blockIdx.x;
    const int g    = (bid & 7) + 8 * ((bid >> 3) & 3);
    const int qt   = bid >> 5;
    const int b    = g >> 3;
    const int ct   = g & 7;

    const int lane = t & 63;
    const int wv   = t >> 6;
    const int quad = lane >> 4;
    const int l15  = lane & 15;

    const int qrow0 = b * NQ + qt * QT;
    const int cbase = ct * CT;

    float4 qv = qp[qrow0 + wv * 16 + l15];
    const float qx = qv.x, qy = qv.y, qz = qv.z, qw = qv.w;

    const int rp  = (t & 7) + 8 * wv;
    const int c4l = (t >> 3) & 7;

    const float*  vb   = v + (size_t)b * NF * CC + cbase;
    const float4* kp4g = (const float4*)(kp3 + (size_t)b * NF * 3);

    floatx4 acc[6];
#pragma unroll
    for (int cs = 0; cs < 6; ++cs) acc[cs] = (floatx4){0.f, 0.f, 0.f, 0.f};

    float va0[3][4], va1[3][4];
    float4 kpld = make_float4(0.f, 0.f, 0.f, 0.f);

#pragma unroll
    for (int rep = 0; rep < 3; ++rep) {
        int col = 4 * (c4l + 8 * rep);
        const float4* p0 = (const float4*)(vb + (size_t)(2 * rp) * CC + col);
        float4 a = p0[0];
        float4 bq = p0[CC / 4];
        va0[rep][0] = a.x;  va0[rep][1] = a.y;  va0[rep][2] = a.z;  va0[rep][3] = a.w;
        va1[rep][0] = bq.x; va1[rep][1] = bq.y; va1[rep][2] = bq.z; va1[rep][3] = bq.w;
    }
    if (t < 96) kpld = kp4g[t];

    for (int ch = 0; ch < NCH; ++ch) {
        const int p = ch & 1;
#pragma unroll
        for (int rep = 0; rep < 3; ++rep) {
            int c0 = 4 * (c4l + 8 * rep);
#pragma unroll
            for (int w = 0; w < 4; ++w) {
                unsigned int pk = f2bf(va0[rep][w]) | (f2bf(va1[rep][w]) << 16);
                vTd[p][(c0 + w) * 68 + (rp ^ (4 * c4l))] = pk;
            }
        }
        if (t < 96) kplB[p][t] = kpld;
        __syncthreads();

        if (ch + 1 < NCH) {
            int m0 = (ch + 1) * BK;
#pragma unroll
            for (int rep = 0; rep < 3; ++rep) {
                int col = 4 * (c4l + 8 * rep);
                const float4* p0 = (const float4*)(vb + (size_t)(m0 + 2 * rp) * CC + col);
                float4 a = p0[0];
                float4 bq = p0[CC / 4];
                va0[rep][0] = a.x;  va0[rep][1] = a.y;  va0[rep][2] = a.z;  va0[rep][3] = a.w;
                va1[rep][0] = bq.x; va1[rep][1] = bq.y; va1[rep][2] = bq.z; va1[rep][3] = bq.w;
            }
            if (t < 96) kpld = kp4g[(ch + 1) * 96 + t];
        }

#pragma unroll
        for (int kk = 0; kk < BK; kk += 32) {
            union { float4 v4[6]; float f[24]; } kq;
            const int kb4 = (kk * 3) / 4 + 6 * quad;
#pragma unroll
            for (int i = 0; i < 6; ++i) kq.v4[i] = kplB[p][kb4 + i];

            union { short8 s; unsigned int d[4]; } af;
#pragma unroll
            for (int j = 0; j < 8; j += 2) {
                float s0 = fmaf(qx, kq.f[3 * j],
                           fmaf(qy, kq.f[3 * j + 1],
                           fmaf(qz, kq.f[3 * j + 2], qw)));
                float s1 = fmaf(qx, kq.f[3 * j + 3],
                           fmaf(qy, kq.f[3 * j + 4],
                           fmaf(qz, kq.f[3 * j + 5], qw)));
                af.d[j >> 1] = f2bf(EXP2F(s0)) | (f2bf(EXP2F(s1)) << 16);
            }

#pragma unroll
            for (int cs = 0; cs < 6; ++cs) {
                int c  = cs * 16 + l15;
                int d0 = ((kk >> 1) + 4 * quad) ^ (4 * ((c >> 2) & 7));
                union { uint4 u; short8 s; } bw;
                bw.u = *(const uint4*)&vTd[p][c * 68 + d0];
                acc[cs] = __builtin_amdgcn_mfma_f32_16x16x32_bf16(
                    af.s, bw.s, acc[cs], 0, 0, 0);
            }
        }
        __syncthreads();
    }

#pragma unroll
    for (int vv = 0; vv < 4; ++vv) {
        int row = qrow0 + wv * 16 + quad * 4 + vv;
        float lv = rstat[row].y;
        float* orow = out + (size_t)row * CC + cbase + l15;
#pragma unroll
        for (int cs = 0; cs < 6; ++cs)
            orow[cs * 16] = acc[cs][vv] * lv;
    }
}

// ---------------------------------------------------------------------------
extern "C" void kernel_launch(void* const* d_in, const int* in_sizes, int n_in,
                              void* d_out, int out_size, void* d_ws, size_t ws_size,
                              hipStream_t stream) {
    const float* q  = (const float*)d_in[0];
    const float* k  = (const float*)d_in[1];
    const float* v  = (const float*)d_in[2];
    const float* W1 = (const float*)d_in[3];
    const float* b1 = (const float*)d_in[4];
    const float* W2 = (const float*)d_in[5];
    const float* b2 = (const float*)d_in[6];
    float* out = (float*)d_out;

    // ws layout: kp3 (768K) | qp (128K) | rstat (64K) | vpk (96M) | partials (72M)
    float*  kp3   = (float*)d_ws;
    float4* qpW   = (float4*)((char*)d_ws + (size_t)Bt * NF * 3 * 4);
    float2* rstat = (float2*)((char*)d_ws + (size_t)Bt * NF * 3 * 4 + (size_t)Bt * NQ * 16);
    char*   vpk   = (char*)d_ws + 983040;
    float*  part  = (float*)((char*)d_ws + 983040 + (size_t)NTILE * TILEB);
    const size_t need = 983040 + (size_t)NTILE * TILEB
                      + (size_t)3 * Bt * NQ * CC * 4;   // ~177.1 MB

    hipLaunchKernelGGL(prep_kernel, dim3((Bt * NQ + Bt * NF) / 256), dim3(256), 0, stream,
                       q, k, W1, b1, W2, b2, qpW, kp3);
    hipLaunchKernelGGL(stats_kernel, dim3(Bt * (NQ / 16)), dim3(256), 0, stream,
                       qpW, kp3, rstat);

    if (ws_size >= need) {
        hipLaunchKernelGGL(prep_v_kernel, dim3(Bt * 512 * 12), dim3(256), 0, stream,
                           v, vpk);
        hipLaunchKernelGGL(attn_main32_kernel, dim3(Bt * 16 * NFS), dim3(512), 0, stream,
                           vpk, qpW, kp3, out, part);
        hipLaunchKernelGGL(reduce_kernel, dim3(2048), dim3(256), 0, stream,
                           out, part, rstat);
    } else {
        // workspace too small for prepack+partials: proven fallback path
        hipLaunchKernelGGL(attn_mfma_kernel, dim3(Bt * (NQ / QT) * (CC / CT)), dim3(THR), 0, stream,
                           v, qpW, kp3, rstat, out);
    }
}